// Round 1
// baseline (1249.020 us; speedup 1.0000x reference)
//
#include <hip/hip_runtime.h>
#include <hip/hip_bf16.h>

// GCN forward: h1 = relu(Ahat (X W1) + b1); h2 = Ahat (h1 W2) + b2; out = segment_mean(h2, batch)
// Ahat = D^-1/2 (A+I) D^-1/2 applied as: y = dinv * (X W); acc[v] = y[v] + sum_{e: col=v} y[row_e];
// out_conv[v] = dinv[v] * acc[v] + b.

__device__ __forceinline__ void atomAdd(float* p, float v) {
#if defined(__HIP_PLATFORM_AMD__)
  unsafeAtomicAdd(p, v);   // native global_atomic_add_f32
#else
  atomicAdd(p, v);
#endif
}

__global__ __launch_bounds__(256) void k_fill1(float* __restrict__ p, int n) {
  int i = blockIdx.x * 256 + threadIdx.x;
  if (i < n) p[i] = 1.0f;
}

__global__ __launch_bounds__(256) void k_deg(const int* __restrict__ col, float* __restrict__ deg, int E) {
  int e = blockIdx.x * 256 + threadIdx.x;
  if (e < E) atomAdd(&deg[col[e]], 1.0f);
}

__global__ __launch_bounds__(256) void k_rsqrt(float* __restrict__ p, int n) {
  int i = blockIdx.x * 256 + threadIdx.x;
  if (i < n) p[i] = rsqrtf(p[i]);
}

// GEMM1: y[v,:] = dinv[v] * (x[v,:] @ W[128,128]); acc = y (self-loop init).
// Block: 32 nodes x 128 cols, two 64-col passes. 256 threads, 8 outputs each.
__global__ __launch_bounds__(256) void k_gemm1(
    const float* __restrict__ x, const float* __restrict__ W,
    const float* __restrict__ dinv, float* __restrict__ y,
    float* __restrict__ acc, int N)
{
  __shared__ float Xt[128][36];   // transposed x tile, pad 36 for bank spread (16B-aligned rows)
  __shared__ float Wl[128][64];
  const int tid = threadIdx.x;
  const int v0 = blockIdx.x * 32;

  { // stage Xt: thread loads 16 floats of one node row, writes transposed
    int vn = tid >> 3;                 // 0..31
    int c0 = (tid & 7) << 4;           // 0..112
    int vv = v0 + vn; if (vv >= N) vv = N - 1;
    const float4* xr = (const float4*)(x + (size_t)vv * 128 + c0);
#pragma unroll
    for (int i = 0; i < 4; ++i) {
      float4 t = xr[i];
      int k = c0 + (i << 2);
      Xt[k + 0][vn] = t.x; Xt[k + 1][vn] = t.y; Xt[k + 2][vn] = t.z; Xt[k + 3][vn] = t.w;
    }
  }

  const int cg = tid & 15;           // 4 cols: 4*cg
  const int ng = tid >> 4;           // 2 nodes: 2*ng
  const int va = v0 + 2 * ng, vb = va + 1;
  const float dva = dinv[va < N ? va : N - 1];
  const float dvb = dinv[vb < N ? vb : N - 1];

  for (int h = 0; h < 2; ++h) {
    __syncthreads();                 // Xt ready (h=0) / previous compute done (h=1)
    { // stage W columns [64h, 64h+64)
      const float4* Wg = (const float4*)W;   // each row = 32 float4
      for (int idx = tid; idx < 2048; idx += 256) {
        int r = idx >> 4, q = idx & 15;
        ((float4*)&Wl[r][0])[q] = Wg[r * 32 + (h << 4) + q];
      }
    }
    __syncthreads();
    float ca[4] = {0.f, 0.f, 0.f, 0.f}, cb[4] = {0.f, 0.f, 0.f, 0.f};
    for (int k = 0; k < 128; ++k) {
      float2 a = *(const float2*)&Xt[k][ng << 1];
      float4 w = *(const float4*)&Wl[k][cg << 2];
      ca[0] += a.x * w.x; ca[1] += a.x * w.y; ca[2] += a.x * w.z; ca[3] += a.x * w.w;
      cb[0] += a.y * w.x; cb[1] += a.y * w.y; cb[2] += a.y * w.z; cb[3] += a.y * w.w;
    }
    if (va < N) {
      size_t base = (size_t)va * 128 + (h << 6) + (cg << 2);
      float4 r = make_float4(dva * ca[0], dva * ca[1], dva * ca[2], dva * ca[3]);
      *(float4*)(y + base) = r; *(float4*)(acc + base) = r;
    }
    if (vb < N) {
      size_t base = (size_t)vb * 128 + (h << 6) + (cg << 2);
      float4 r = make_float4(dvb * cb[0], dvb * cb[1], dvb * cb[2], dvb * cb[3]);
      *(float4*)(y + base) = r; *(float4*)(acc + base) = r;
    }
  }
}

// GEMM2: z[v,:] = dinv[v] * (h[v,:] @ W2[128,64]); acc2 = z. h lives in `hbuf` (N x 128).
__global__ __launch_bounds__(256) void k_gemm2(
    const float* __restrict__ hbuf, const float* __restrict__ W,
    const float* __restrict__ dinv, float* __restrict__ z,
    float* __restrict__ acc2, int N)
{
  __shared__ float Xt[128][36];
  __shared__ float Wl[128][64];
  const int tid = threadIdx.x;
  const int v0 = blockIdx.x * 32;

  {
    int vn = tid >> 3;
    int c0 = (tid & 7) << 4;
    int vv = v0 + vn; if (vv >= N) vv = N - 1;
    const float4* xr = (const float4*)(hbuf + (size_t)vv * 128 + c0);
#pragma unroll
    for (int i = 0; i < 4; ++i) {
      float4 t = xr[i];
      int k = c0 + (i << 2);
      Xt[k + 0][vn] = t.x; Xt[k + 1][vn] = t.y; Xt[k + 2][vn] = t.z; Xt[k + 3][vn] = t.w;
    }
  }
  { // stage full W2 (128x64)
    const float4* Wg = (const float4*)W;   // each row = 16 float4
    for (int idx = tid; idx < 2048; idx += 256) {
      int r = idx >> 4, q = idx & 15;
      ((float4*)&Wl[r][0])[q] = Wg[r * 16 + q];
    }
  }
  __syncthreads();

  const int cg = tid & 15;
  const int ng = tid >> 4;
  const int va = v0 + 2 * ng, vb = va + 1;
  const float dva = dinv[va < N ? va : N - 1];
  const float dvb = dinv[vb < N ? vb : N - 1];

  float ca[4] = {0.f, 0.f, 0.f, 0.f}, cb[4] = {0.f, 0.f, 0.f, 0.f};
  for (int k = 0; k < 128; ++k) {
    float2 a = *(const float2*)&Xt[k][ng << 1];
    float4 w = *(const float4*)&Wl[k][cg << 2];
    ca[0] += a.x * w.x; ca[1] += a.x * w.y; ca[2] += a.x * w.z; ca[3] += a.x * w.w;
    cb[0] += a.y * w.x; cb[1] += a.y * w.y; cb[2] += a.y * w.z; cb[3] += a.y * w.w;
  }
  if (va < N) {
    size_t base = (size_t)va * 64 + (cg << 2);
    float4 r = make_float4(dva * ca[0], dva * ca[1], dva * ca[2], dva * ca[3]);
    *(float4*)(z + base) = r; *(float4*)(acc2 + base) = r;
  }
  if (vb < N) {
    size_t base = (size_t)vb * 64 + (cg << 2);
    float4 r = make_float4(dvb * cb[0], dvb * cb[1], dvb * cb[2], dvb * cb[3]);
    *(float4*)(z + base) = r; *(float4*)(acc2 + base) = r;
  }
}

// scatter F=128: one wave per edge, lane handles 2 dims (float2)
__global__ __launch_bounds__(256) void k_scatter128(
    const int* __restrict__ rows, const int* __restrict__ cols,
    const float* __restrict__ y, float* __restrict__ acc, int E)
{
  int wid = blockIdx.x * 4 + (threadIdx.x >> 6);
  if (wid >= E) return;
  int lane = threadIdx.x & 63;
  int r = rows[wid], c = cols[wid];
  float2 v = ((const float2*)(y + (size_t)r * 128))[lane];
  float* dst = acc + (size_t)c * 128 + 2 * lane;
  atomAdd(dst, v.x);
  atomAdd(dst + 1, v.y);
}

// scatter F=64: one wave per edge, lane handles 1 dim
__global__ __launch_bounds__(256) void k_scatter64(
    const int* __restrict__ rows, const int* __restrict__ cols,
    const float* __restrict__ y, float* __restrict__ acc, int E)
{
  int wid = blockIdx.x * 4 + (threadIdx.x >> 6);
  if (wid >= E) return;
  int lane = threadIdx.x & 63;
  int r = rows[wid], c = cols[wid];
  float v = y[(size_t)r * 64 + lane];
  atomAdd(acc + (size_t)c * 64 + lane, v);
}

// post1: h = relu(dinv*acc + b1), in place in acc
__global__ __launch_bounds__(256) void k_post1(
    float* __restrict__ acc, const float* __restrict__ dinv,
    const float* __restrict__ b1, int total)
{
  int i = blockIdx.x * 256 + threadIdx.x;
  if (i >= total) return;
  int v = i >> 7, d = i & 127;
  float val = dinv[v] * acc[i] + b1[d];
  acc[i] = fmaxf(val, 0.f);
}

// post2 + pool: val = dinv*acc2 + b2; atomic into per-graph sums; count nodes
__global__ __launch_bounds__(256) void k_pool(
    const float* __restrict__ acc2, const float* __restrict__ dinv,
    const float* __restrict__ b2, const int* __restrict__ batch,
    float* __restrict__ out, float* __restrict__ counts, int N)
{
  int i = blockIdx.x * 256 + threadIdx.x;
  if (i >= N * 64) return;
  int v = i >> 6, d = i & 63;
  float val = dinv[v] * acc2[i] + b2[d];
  int g = batch[v];
  atomAdd(out + g * 64 + d, val);
  if (d == 0) atomAdd(counts + g, 1.f);
}

__global__ __launch_bounds__(256) void k_final(float* __restrict__ out,
                                               const float* __restrict__ counts, int total)
{
  int i = blockIdx.x * 256 + threadIdx.x;
  if (i >= total) return;
  out[i] /= fmaxf(counts[i >> 6], 1.f);
}

extern "C" void kernel_launch(void* const* d_in, const int* in_sizes, int n_in,
                              void* d_out, int out_size, void* d_ws, size_t ws_size,
                              hipStream_t stream) {
  const float* x    = (const float*)d_in[0];
  const int*   eidx = (const int*)d_in[1];
  const int*   batch= (const int*)d_in[2];
  const float* W1   = (const float*)d_in[3];
  const float* b1   = (const float*)d_in[4];
  const float* W2   = (const float*)d_in[5];
  const float* b2   = (const float*)d_in[6];
  float* out = (float*)d_out;

  const int N = in_sizes[2];          // 100000
  const int E = in_sizes[1] / 2;      // 640000
  const int G = out_size / 64;        // 256

  const int* rows = eidx;             // edge_index[0] = sources
  const int* cols = eidx + E;         // edge_index[1] = targets

  // workspace layout (floats): [deg/dinv: N][ybuf: N*128][acc: N*128][counts: G]
  float* deg    = (float*)d_ws;
  float* ybuf   = deg + N;
  float* acc    = ybuf + (size_t)N * 128;
  float* counts = acc + (size_t)N * 128;
  float* zbuf   = ybuf;                       // layer2: z in first N*64 of ybuf
  float* acc2   = ybuf + (size_t)N * 64;      // layer2 accumulator in second half

  hipMemsetAsync(d_out, 0, (size_t)out_size * sizeof(float), stream);
  hipMemsetAsync(counts, 0, (size_t)G * sizeof(float), stream);

  const int B = 256;
  // degrees (self-loop => init 1)
  k_fill1<<<(N + B - 1) / B, B, 0, stream>>>(deg, N);
  k_deg<<<(E + B - 1) / B, B, 0, stream>>>(cols, deg, E);
  k_rsqrt<<<(N + B - 1) / B, B, 0, stream>>>(deg, N);   // deg now holds dinv

  // layer 1
  k_gemm1<<<(N + 31) / 32, B, 0, stream>>>(x, W1, deg, ybuf, acc, N);
  k_scatter128<<<(E + 3) / 4, B, 0, stream>>>(rows, cols, ybuf, acc, E);
  k_post1<<<((size_t)N * 128 + B - 1) / B, B, 0, stream>>>(acc, deg, b1, N * 128);

  // layer 2 (h is in acc)
  k_gemm2<<<(N + 31) / 32, B, 0, stream>>>(acc, W2, deg, zbuf, acc2, N);
  k_scatter64<<<(E + 3) / 4, B, 0, stream>>>(rows, cols, zbuf, acc2, E);

  // pool + mean
  k_pool<<<((size_t)N * 64 + B - 1) / B, B, 0, stream>>>(acc2, deg, b2, batch, out, counts, N);
  k_final<<<(out_size + B - 1) / B, B, 0, stream>>>(out, counts, out_size);
}

// Round 2
// 776.008 us; speedup vs baseline: 1.6095x; 1.6095x over previous
//
#include <hip/hip_runtime.h>
#include <hip/hip_bf16.h>

// GCN forward, CSR-gather formulation:
//   dinv[v] = rsqrt(1 + indeg[v])
//   y = dinv .* (X W1)                         (k_gemm1)
//   h[v] = relu(dinv[v]*(y[v] + sum_{u->v} y[u]) + b1)   (staged inside k_gemm2_fused)
//   z = dinv .* (h W2)                         (k_gemm2_fused)
//   o[v] = dinv[v]*(z[v] + sum_{u->v} z[u]) + b2 ; out[g] = mean_v o[v]  (k_agg64pool)

__device__ __forceinline__ void atomAddF(float* p, float v) {
  unsafeAtomicAdd(p, v);   // native global_atomic_add_f32
}

// ---------- degree / CSR build ----------
__global__ __launch_bounds__(256) void k_count(const int* __restrict__ col,
                                               int* __restrict__ deg, int E) {
  int e = blockIdx.x * 256 + threadIdx.x;
  if (e < E) atomicAdd(&deg[col[e]], 1);
}

__global__ __launch_bounds__(256) void k_blocksum(const int* __restrict__ deg,
                                                  int* __restrict__ partial, int N) {
  __shared__ int sh[256];
  int t = threadIdx.x, i = blockIdx.x * 256 + t;
  sh[t] = (i < N) ? deg[i] : 0;
  __syncthreads();
  for (int o = 128; o > 0; o >>= 1) {
    if (t < o) sh[t] += sh[t + o];
    __syncthreads();
  }
  if (t == 0) partial[blockIdx.x] = sh[0];
}

__global__ __launch_bounds__(512) void k_scanpartial(int* __restrict__ partial, int nb) {
  __shared__ int sh[512];
  int t = threadIdx.x;
  int v = (t < nb) ? partial[t] : 0;
  sh[t] = v;
  __syncthreads();
  for (int o = 1; o < 512; o <<= 1) {
    int x = (t >= o) ? sh[t - o] : 0;
    __syncthreads();
    sh[t] += x;
    __syncthreads();
  }
  if (t < nb) partial[t] = sh[t] - v;   // exclusive
}

// exclusive scan within block + partial offset; also cursor init (in deg) and dinv
__global__ __launch_bounds__(256) void k_scanblock(int* __restrict__ deg,
    const int* __restrict__ partial, int* __restrict__ off,
    float* __restrict__ dinv, int N) {
  __shared__ int sh[256];
  int t = threadIdx.x, b = blockIdx.x, i = b * 256 + t;
  int v = (i < N) ? deg[i] : 0;
  sh[t] = v;
  __syncthreads();
  for (int o = 1; o < 256; o <<= 1) {
    int x = (t >= o) ? sh[t - o] : 0;
    __syncthreads();
    sh[t] += x;
    __syncthreads();
  }
  if (i < N) {
    int excl = partial[b] + sh[t] - v;
    off[i] = excl;
    deg[i] = excl;                       // deg becomes the fill cursor
    dinv[i] = rsqrtf((float)v + 1.0f);   // +1 self-loop
    if (i == N - 1) off[N] = excl + v;
  }
}

__global__ __launch_bounds__(256) void k_fillcsr(const int* __restrict__ rows,
    const int* __restrict__ cols, int* __restrict__ cursor,
    int* __restrict__ csrsrc, int E) {
  int e = blockIdx.x * 256 + threadIdx.x;
  if (e < E) {
    int pos = atomicAdd(&cursor[cols[e]], 1);
    csrsrc[pos] = rows[e];
  }
}

// ---------- GEMM1: y[v,:] = dinv[v] * (x[v,:] @ W1[128,128]) ----------
// Block: 32 nodes x 128 cols in two 64-col passes; 256 threads, 8 outputs each.
__global__ __launch_bounds__(256) void k_gemm1(
    const float* __restrict__ x, const float* __restrict__ W,
    const float* __restrict__ dinv, float* __restrict__ y, int N)
{
  __shared__ float Xt[128][36];
  __shared__ float Wl[128][64];
  const int tid = threadIdx.x;
  const int v0 = blockIdx.x * 32;

  { // stage Xt transposed
    int vn = tid >> 3;
    int c0 = (tid & 7) << 4;
    int vv = v0 + vn; if (vv >= N) vv = N - 1;
    const float4* xr = (const float4*)(x + (size_t)vv * 128 + c0);
#pragma unroll
    for (int i = 0; i < 4; ++i) {
      float4 t = xr[i];
      int k = c0 + (i << 2);
      Xt[k + 0][vn] = t.x; Xt[k + 1][vn] = t.y; Xt[k + 2][vn] = t.z; Xt[k + 3][vn] = t.w;
    }
  }

  const int cg = tid & 15;
  const int ng = tid >> 4;
  const int va = v0 + 2 * ng, vb = va + 1;
  const float dva = dinv[va < N ? va : N - 1];
  const float dvb = dinv[vb < N ? vb : N - 1];

  for (int h = 0; h < 2; ++h) {
    __syncthreads();
    { // stage W cols [64h, 64h+64)
      const float4* Wg = (const float4*)W;
      for (int idx = tid; idx < 2048; idx += 256) {
        int r = idx >> 4, q = idx & 15;
        ((float4*)&Wl[r][0])[q] = Wg[r * 32 + (h << 4) + q];
      }
    }
    __syncthreads();
    float ca[4] = {0.f, 0.f, 0.f, 0.f}, cb[4] = {0.f, 0.f, 0.f, 0.f};
    for (int k = 0; k < 128; ++k) {
      float2 a = *(const float2*)&Xt[k][ng << 1];
      float4 w = *(const float4*)&Wl[k][cg << 2];
      ca[0] += a.x * w.x; ca[1] += a.x * w.y; ca[2] += a.x * w.z; ca[3] += a.x * w.w;
      cb[0] += a.y * w.x; cb[1] += a.y * w.y; cb[2] += a.y * w.z; cb[3] += a.y * w.w;
    }
    if (va < N) {
      size_t base = (size_t)va * 128 + (h << 6) + (cg << 2);
      *(float4*)(y + base) = make_float4(dva * ca[0], dva * ca[1], dva * ca[2], dva * ca[3]);
    }
    if (vb < N) {
      size_t base = (size_t)vb * 128 + (h << 6) + (cg << 2);
      *(float4*)(y + base) = make_float4(dvb * cb[0], dvb * cb[1], dvb * cb[2], dvb * cb[3]);
    }
  }
}

// ---------- GEMM2 fused with layer-1 aggregation ----------
// Staging computes h[v,:] = relu(dinv[v]*(y[v]+sum_in y[u]) + b1) directly into LDS,
// then z[v,:] = dinv[v] * (h[v,:] @ W2[128,64]).
__global__ __launch_bounds__(256) void k_gemm2_fused(
    const float* __restrict__ y, const int* __restrict__ off, const int* __restrict__ src,
    const float* __restrict__ W, const float* __restrict__ dinv,
    const float* __restrict__ b1, float* __restrict__ z, int N)
{
  __shared__ float Xt[128][36];
  __shared__ float Wl[128][64];
  const int tid = threadIdx.x;
  const int v0 = blockIdx.x * 32;

  { // stage full W2 (128x64)
    const float4* Wg = (const float4*)W;
    for (int idx = tid; idx < 2048; idx += 256) {
      int r = idx >> 4, q = idx & 15;
      ((float4*)&Wl[r][0])[q] = Wg[r * 16 + q];
    }
  }
  { // build h tile: 8 threads/node, 16 dims each
    int vn = tid >> 3;
    int c0 = (tid & 7) << 4;
    int vv = v0 + vn;
    int vc = (vv < N) ? vv : N - 1;
    float acc[16];
    const float4* yr = (const float4*)(y + (size_t)vc * 128 + c0);
#pragma unroll
    for (int q = 0; q < 4; ++q) {
      float4 t = yr[q];
      acc[4*q+0] = t.x; acc[4*q+1] = t.y; acc[4*q+2] = t.z; acc[4*q+3] = t.w;
    }
    int e0 = off[vc], e1 = off[vc + 1];
    int i = e0;
    for (; i + 1 < e1; i += 2) {   // unroll 2 for MLP
      int u0 = src[i], u1 = src[i + 1];
      const float4* a0 = (const float4*)(y + (size_t)u0 * 128 + c0);
      const float4* a1 = (const float4*)(y + (size_t)u1 * 128 + c0);
#pragma unroll
      for (int q = 0; q < 4; ++q) {
        float4 t0 = a0[q], t1 = a1[q];
        acc[4*q+0] += t0.x + t1.x; acc[4*q+1] += t0.y + t1.y;
        acc[4*q+2] += t0.z + t1.z; acc[4*q+3] += t0.w + t1.w;
      }
    }
    if (i < e1) {
      const float4* a0 = (const float4*)(y + (size_t)src[i] * 128 + c0);
#pragma unroll
      for (int q = 0; q < 4; ++q) {
        float4 t0 = a0[q];
        acc[4*q+0] += t0.x; acc[4*q+1] += t0.y; acc[4*q+2] += t0.z; acc[4*q+3] += t0.w;
      }
    }
    float d = dinv[vc];
#pragma unroll
    for (int j = 0; j < 16; ++j)
      Xt[c0 + j][vn] = fmaxf(fmaf(d, acc[j], b1[c0 + j]), 0.f);
  }
  __syncthreads();

  const int cg = tid & 15;
  const int ng = tid >> 4;
  const int va = v0 + 2 * ng, vb = va + 1;
  const float dva = dinv[va < N ? va : N - 1];
  const float dvb = dinv[vb < N ? vb : N - 1];

  float ca[4] = {0.f, 0.f, 0.f, 0.f}, cb[4] = {0.f, 0.f, 0.f, 0.f};
  for (int k = 0; k < 128; ++k) {
    float2 a = *(const float2*)&Xt[k][ng << 1];
    float4 w = *(const float4*)&Wl[k][cg << 2];
    ca[0] += a.x * w.x; ca[1] += a.x * w.y; ca[2] += a.x * w.z; ca[3] += a.x * w.w;
    cb[0] += a.y * w.x; cb[1] += a.y * w.y; cb[2] += a.y * w.z; cb[3] += a.y * w.w;
  }
  if (va < N) {
    size_t base = (size_t)va * 64 + (cg << 2);
    *(float4*)(z + base) = make_float4(dva * ca[0], dva * ca[1], dva * ca[2], dva * ca[3]);
  }
  if (vb < N) {
    size_t base = (size_t)vb * 64 + (cg << 2);
    *(float4*)(z + base) = make_float4(dvb * cb[0], dvb * cb[1], dvb * cb[2], dvb * cb[3]);
  }
}

// ---------- layer-2 aggregation + bias + mean-pool ----------
__global__ __launch_bounds__(256) void k_agg64pool(
    const float* __restrict__ z, const int* __restrict__ off, const int* __restrict__ src,
    const float* __restrict__ dinv, const float* __restrict__ b2,
    const int* __restrict__ batch, float* __restrict__ out,
    float* __restrict__ counts, int N)
{
  int v = blockIdx.x * 4 + (threadIdx.x >> 6);
  if (v >= N) return;
  int lane = threadIdx.x & 63;
  float s = z[(size_t)v * 64 + lane];
  int e0 = off[v], e1 = off[v + 1];
  int i = e0;
  for (; i + 1 < e1; i += 2) {
    int u0 = src[i], u1 = src[i + 1];
    s += z[(size_t)u0 * 64 + lane] + z[(size_t)u1 * 64 + lane];
  }
  if (i < e1) s += z[(size_t)src[i] * 64 + lane];
  float val = fmaf(dinv[v], s, b2[lane]);
  int g = batch[v];
  atomAddF(out + (size_t)g * 64 + lane, val);
  if (lane == 0) atomAddF(counts + g, 1.f);
}

__global__ __launch_bounds__(256) void k_final(float* __restrict__ out,
                                               const float* __restrict__ counts, int total) {
  int i = blockIdx.x * 256 + threadIdx.x;
  if (i >= total) return;
  out[i] /= fmaxf(counts[i >> 6], 1.f);
}

extern "C" void kernel_launch(void* const* d_in, const int* in_sizes, int n_in,
                              void* d_out, int out_size, void* d_ws, size_t ws_size,
                              hipStream_t stream) {
  const float* x     = (const float*)d_in[0];
  const int*   eidx  = (const int*)d_in[1];
  const int*   batch = (const int*)d_in[2];
  const float* W1    = (const float*)d_in[3];
  const float* b1    = (const float*)d_in[4];
  const float* W2    = (const float*)d_in[5];
  const float* b2    = (const float*)d_in[6];
  float* out = (float*)d_out;

  const int N = in_sizes[2];          // 100000
  const int E = in_sizes[1] / 2;      // 640000
  const int G = out_size / 64;        // 256

  const int* rows = eidx;             // sources
  const int* cols = eidx + E;         // targets

  // workspace: [ybuf N*128 f][zbuf N*64 f][dinv N f][deg/cursor N i][off N+1 i][partial 512 i][csrsrc E i][counts G f]
  float* ybuf   = (float*)d_ws;
  float* zbuf   = ybuf + (size_t)N * 128;
  float* dinv   = zbuf + (size_t)N * 64;
  int*   deg    = (int*)(dinv + N);
  int*   off    = deg + N;
  int*   partial= off + N + 1;
  int*   csrsrc = partial + 512;
  float* counts = (float*)(csrsrc + E);

  const int B = 256;
  const int nb = (N + B - 1) / B;     // 391 <= 512

  hipMemsetAsync(deg, 0, (size_t)N * sizeof(int), stream);
  hipMemsetAsync(d_out, 0, (size_t)out_size * sizeof(float), stream);
  hipMemsetAsync(counts, 0, (size_t)G * sizeof(float), stream);

  // CSR build + dinv
  k_count<<<(E + B - 1) / B, B, 0, stream>>>(cols, deg, E);
  k_blocksum<<<nb, B, 0, stream>>>(deg, partial, N);
  k_scanpartial<<<1, 512, 0, stream>>>(partial, nb);
  k_scanblock<<<nb, B, 0, stream>>>(deg, partial, off, dinv, N);
  k_fillcsr<<<(E + B - 1) / B, B, 0, stream>>>(rows, cols, deg, csrsrc, E);

  // layer 1 transform
  k_gemm1<<<(N + 31) / 32, B, 0, stream>>>(x, W1, dinv, ybuf, N);
  // layer 1 aggregate + relu fused into layer 2 transform
  k_gemm2_fused<<<(N + 31) / 32, B, 0, stream>>>(ybuf, off, csrsrc, W2, dinv, b1, zbuf, N);
  // layer 2 aggregate + bias + mean pool
  k_agg64pool<<<(N + 3) / 4, B, 0, stream>>>(zbuf, off, csrsrc, dinv, b2, batch, out, counts, N);
  k_final<<<(out_size + B - 1) / B, B, 0, stream>>>(out, counts, out_size);
}

// Round 3
// 338.542 us; speedup vs baseline: 3.6894x; 2.2922x over previous
//
#include <hip/hip_runtime.h>
#include <hip/hip_bf16.h>

// GCN forward, CSR-gather formulation, atomic-free pooling:
//   dinv[v] = rsqrt(1 + indeg[v])
//   y = dinv .* (X W1)                                   (k_gemm1)
//   h[v] = relu(dinv[v]*(y[v] + sum_{u->v} y[u]) + b1)   (staged inside k_gemm2_fused)
//   z = dinv .* (h W2)                                   (k_gemm2_fused)
//   S[g] = sum_{v in g} dinv[v]*(z[v] + sum_{u->v} z[u]) (k_aggpool, per-graph-segment blocks)
//   out[g] = S[g]/n_g + b2                               (k_final)

__device__ __forceinline__ void atomAddF(float* p, float v) {
  unsafeAtomicAdd(p, v);
}

// ---------- degree / CSR build ----------
__global__ __launch_bounds__(256) void k_count(const int* __restrict__ col,
                                               int* __restrict__ deg, int E) {
  int e = blockIdx.x * 256 + threadIdx.x;
  if (e < E) atomicAdd(&deg[col[e]], 1);
}

__global__ __launch_bounds__(256) void k_blocksum(const int* __restrict__ deg,
                                                  int* __restrict__ partial, int N) {
  __shared__ int sh[256];
  int t = threadIdx.x, i = blockIdx.x * 256 + t;
  sh[t] = (i < N) ? deg[i] : 0;
  __syncthreads();
  for (int o = 128; o > 0; o >>= 1) {
    if (t < o) sh[t] += sh[t + o];
    __syncthreads();
  }
  if (t == 0) partial[blockIdx.x] = sh[0];
}

__global__ __launch_bounds__(512) void k_scanpartial(int* __restrict__ partial, int nb) {
  __shared__ int sh[512];
  int t = threadIdx.x;
  int v = (t < nb) ? partial[t] : 0;
  sh[t] = v;
  __syncthreads();
  for (int o = 1; o < 512; o <<= 1) {
    int x = (t >= o) ? sh[t - o] : 0;
    __syncthreads();
    sh[t] += x;
    __syncthreads();
  }
  if (t < nb) partial[t] = sh[t] - v;   // exclusive
}

__global__ __launch_bounds__(256) void k_scanblock(int* __restrict__ deg,
    const int* __restrict__ partial, int* __restrict__ off,
    float* __restrict__ dinv, int N) {
  __shared__ int sh[256];
  int t = threadIdx.x, b = blockIdx.x, i = b * 256 + t;
  int v = (i < N) ? deg[i] : 0;
  sh[t] = v;
  __syncthreads();
  for (int o = 1; o < 256; o <<= 1) {
    int x = (t >= o) ? sh[t - o] : 0;
    __syncthreads();
    sh[t] += x;
    __syncthreads();
  }
  if (i < N) {
    int excl = partial[b] + sh[t] - v;
    off[i] = excl;
    deg[i] = excl;                       // becomes fill cursor
    dinv[i] = rsqrtf((float)v + 1.0f);   // +1 self-loop
    if (i == N - 1) off[N] = excl + v;
  }
}

__global__ __launch_bounds__(256) void k_fillcsr(const int* __restrict__ rows,
    const int* __restrict__ cols, int* __restrict__ cursor,
    int* __restrict__ csrsrc, int E) {
  int e = blockIdx.x * 256 + threadIdx.x;
  if (e < E) {
    int pos = atomicAdd(&cursor[cols[e]], 1);
    csrsrc[pos] = rows[e];
  }
}

// graph start offsets: batch is sorted; goff[g] = first i with batch[i] >= g
__global__ __launch_bounds__(256) void k_goff(const int* __restrict__ batch,
                                              int* __restrict__ goff, int N, int G) {
  int g = blockIdx.x * 256 + threadIdx.x;
  if (g > G) return;
  int lo = 0, hi = N;
  while (lo < hi) {
    int m = (lo + hi) >> 1;
    if (batch[m] < g) lo = m + 1; else hi = m;
  }
  goff[g] = lo;
}

// ---------- GEMM1: y[v,:] = dinv[v] * (x[v,:] @ W1[128,128]) ----------
__global__ __launch_bounds__(256) void k_gemm1(
    const float* __restrict__ x, const float* __restrict__ W,
    const float* __restrict__ dinv, float* __restrict__ y, int N)
{
  __shared__ float Xt[128][36];
  __shared__ float Wl[128][64];
  const int tid = threadIdx.x;
  const int v0 = blockIdx.x * 32;

  {
    int vn = tid >> 3;
    int c0 = (tid & 7) << 4;
    int vv = v0 + vn; if (vv >= N) vv = N - 1;
    const float4* xr = (const float4*)(x + (size_t)vv * 128 + c0);
#pragma unroll
    for (int i = 0; i < 4; ++i) {
      float4 t = xr[i];
      int k = c0 + (i << 2);
      Xt[k + 0][vn] = t.x; Xt[k + 1][vn] = t.y; Xt[k + 2][vn] = t.z; Xt[k + 3][vn] = t.w;
    }
  }

  const int cg = tid & 15;
  const int ng = tid >> 4;
  const int va = v0 + 2 * ng, vb = va + 1;
  const float dva = dinv[va < N ? va : N - 1];
  const float dvb = dinv[vb < N ? vb : N - 1];

  for (int h = 0; h < 2; ++h) {
    __syncthreads();
    {
      const float4* Wg = (const float4*)W;
      for (int idx = tid; idx < 2048; idx += 256) {
        int r = idx >> 4, q = idx & 15;
        ((float4*)&Wl[r][0])[q] = Wg[r * 32 + (h << 4) + q];
      }
    }
    __syncthreads();
    float ca[4] = {0.f, 0.f, 0.f, 0.f}, cb[4] = {0.f, 0.f, 0.f, 0.f};
    for (int k = 0; k < 128; ++k) {
      float2 a = *(const float2*)&Xt[k][ng << 1];
      float4 w = *(const float4*)&Wl[k][cg << 2];
      ca[0] += a.x * w.x; ca[1] += a.x * w.y; ca[2] += a.x * w.z; ca[3] += a.x * w.w;
      cb[0] += a.y * w.x; cb[1] += a.y * w.y; cb[2] += a.y * w.z; cb[3] += a.y * w.w;
    }
    if (va < N) {
      size_t base = (size_t)va * 128 + (h << 6) + (cg << 2);
      *(float4*)(y + base) = make_float4(dva * ca[0], dva * ca[1], dva * ca[2], dva * ca[3]);
    }
    if (vb < N) {
      size_t base = (size_t)vb * 128 + (h << 6) + (cg << 2);
      *(float4*)(y + base) = make_float4(dvb * cb[0], dvb * cb[1], dvb * cb[2], dvb * cb[3]);
    }
  }
}

// ---------- GEMM2 fused with layer-1 aggregation ----------
__global__ __launch_bounds__(256) void k_gemm2_fused(
    const float* __restrict__ y, const int* __restrict__ off, const int* __restrict__ src,
    const float* __restrict__ W, const float* __restrict__ dinv,
    const float* __restrict__ b1, float* __restrict__ z, int N)
{
  __shared__ float Xt[128][36];
  __shared__ float Wl[128][64];
  const int tid = threadIdx.x;
  const int v0 = blockIdx.x * 32;

  { // stage full W2 (128x64) — loads overlap the gather phase below
    const float4* Wg = (const float4*)W;
    for (int idx = tid; idx < 2048; idx += 256) {
      int r = idx >> 4, q = idx & 15;
      ((float4*)&Wl[r][0])[q] = Wg[r * 16 + q];
    }
  }
  { // build h tile: 8 threads/node, 16 dims each; MLP-4 batched neighbor gather
    int vn = tid >> 3;
    int c0 = (tid & 7) << 4;
    int vv = v0 + vn;
    int vc = (vv < N) ? vv : N - 1;
    float acc[16];
    const float4* yr = (const float4*)(y + (size_t)vc * 128 + c0);
#pragma unroll
    for (int q = 0; q < 4; ++q) {
      float4 t = yr[q];
      acc[4*q+0] = t.x; acc[4*q+1] = t.y; acc[4*q+2] = t.z; acc[4*q+3] = t.w;
    }
    int e0 = off[vc], e1 = off[vc + 1];
    int last = e1 - 1;
    for (int i = e0; i < e1; i += 4) {
      int i1 = i + 1, i2 = i + 2, i3 = i + 3;
      int u0 = src[i];
      int u1 = src[i1 <= last ? i1 : last];
      int u2 = src[i2 <= last ? i2 : last];
      int u3 = src[i3 <= last ? i3 : last];
      float m1 = (i1 <= last) ? 1.f : 0.f;
      float m2 = (i2 <= last) ? 1.f : 0.f;
      float m3 = (i3 <= last) ? 1.f : 0.f;
      const float4* p0 = (const float4*)(y + (size_t)u0 * 128 + c0);
      const float4* p1 = (const float4*)(y + (size_t)u1 * 128 + c0);
      const float4* p2 = (const float4*)(y + (size_t)u2 * 128 + c0);
      const float4* p3 = (const float4*)(y + (size_t)u3 * 128 + c0);
#pragma unroll
      for (int q = 0; q < 4; ++q) {
        float4 t0 = p0[q], t1 = p1[q], t2 = p2[q], t3 = p3[q];
        acc[4*q+0] += t0.x + m1 * t1.x + m2 * t2.x + m3 * t3.x;
        acc[4*q+1] += t0.y + m1 * t1.y + m2 * t2.y + m3 * t3.y;
        acc[4*q+2] += t0.z + m1 * t1.z + m2 * t2.z + m3 * t3.z;
        acc[4*q+3] += t0.w + m1 * t1.w + m2 * t2.w + m3 * t3.w;
      }
    }
    float d = dinv[vc];
#pragma unroll
    for (int j = 0; j < 16; ++j)
      Xt[c0 + j][vn] = fmaxf(fmaf(d, acc[j], b1[c0 + j]), 0.f);
  }
  __syncthreads();

  const int cg = tid & 15;
  const int ng = tid >> 4;
  const int va = v0 + 2 * ng, vb = va + 1;
  const float dva = dinv[va < N ? va : N - 1];
  const float dvb = dinv[vb < N ? vb : N - 1];

  float ca[4] = {0.f, 0.f, 0.f, 0.f}, cb[4] = {0.f, 0.f, 0.f, 0.f};
  for (int k = 0; k < 128; ++k) {
    float2 a = *(const float2*)&Xt[k][ng << 1];
    float4 w = *(const float4*)&Wl[k][cg << 2];
    ca[0] += a.x * w.x; ca[1] += a.x * w.y; ca[2] += a.x * w.z; ca[3] += a.x * w.w;
    cb[0] += a.y * w.x; cb[1] += a.y * w.y; cb[2] += a.y * w.z; cb[3] += a.y * w.w;
  }
  if (va < N) {
    size_t base = (size_t)va * 64 + (cg << 2);
    *(float4*)(z + base) = make_float4(dva * ca[0], dva * ca[1], dva * ca[2], dva * ca[3]);
  }
  if (vb < N) {
    size_t base = (size_t)vb * 64 + (cg << 2);
    *(float4*)(z + base) = make_float4(dvb * cb[0], dvb * cb[1], dvb * cb[2], dvb * cb[3]);
  }
}

// ---------- layer-2 aggregation + pool, atomic-light ----------
// grid = G * 8 blocks; block (g, seg) covers nodes lo+seg*4+w (stride 32) of graph g.
// Each wave: lane = dim, accumulates sum_v dinv[v]*(z[v]+sum_in z[u]) in a register,
// one wave-atomic per wave into out (32 atomics/address total across the grid).
__global__ __launch_bounds__(256) void k_aggpool(
    const float* __restrict__ z, const int* __restrict__ off, const int* __restrict__ src,
    const float* __restrict__ dinv, const int* __restrict__ goff,
    float* __restrict__ out, int N)
{
  int g = blockIdx.x >> 3, seg = blockIdx.x & 7;
  int w = threadIdx.x >> 6, lane = threadIdx.x & 63;
  int lo = goff[g], hi = goff[g + 1];
  float acc = 0.f;
  for (int v = lo + seg * 4 + w; v < hi; v += 32) {
    float sv = z[(size_t)v * 64 + lane];
    int e0 = off[v], e1 = off[v + 1];
    int last = e1 - 1;
    for (int i = e0; i < e1; i += 4) {
      int i1 = i + 1, i2 = i + 2, i3 = i + 3;
      int u0 = src[i];
      int u1 = src[i1 <= last ? i1 : last];
      int u2 = src[i2 <= last ? i2 : last];
      int u3 = src[i3 <= last ? i3 : last];
      float a0 = z[(size_t)u0 * 64 + lane];
      float a1 = z[(size_t)u1 * 64 + lane];
      float a2 = z[(size_t)u2 * 64 + lane];
      float a3 = z[(size_t)u3 * 64 + lane];
      sv += a0;
      sv += (i1 <= last) ? a1 : 0.f;
      sv += (i2 <= last) ? a2 : 0.f;
      sv += (i3 <= last) ? a3 : 0.f;
    }
    acc = fmaf(dinv[v], sv, acc);
  }
  atomAddF(out + (size_t)g * 64 + lane, acc);
}

__global__ __launch_bounds__(256) void k_final(float* __restrict__ out,
    const int* __restrict__ goff, const float* __restrict__ b2, int total) {
  int i = blockIdx.x * 256 + threadIdx.x;
  if (i >= total) return;
  int g = i >> 6, d = i & 63;
  int n = goff[g + 1] - goff[g];
  out[i] = (n > 0) ? out[i] / (float)n + b2[d] : 0.f;
}

extern "C" void kernel_launch(void* const* d_in, const int* in_sizes, int n_in,
                              void* d_out, int out_size, void* d_ws, size_t ws_size,
                              hipStream_t stream) {
  const float* x     = (const float*)d_in[0];
  const int*   eidx  = (const int*)d_in[1];
  const int*   batch = (const int*)d_in[2];
  const float* W1    = (const float*)d_in[3];
  const float* b1    = (const float*)d_in[4];
  const float* W2    = (const float*)d_in[5];
  const float* b2    = (const float*)d_in[6];
  float* out = (float*)d_out;

  const int N = in_sizes[2];          // 100000
  const int E = in_sizes[1] / 2;      // 640000
  const int G = out_size / 64;        // 256

  const int* rows = eidx;             // sources
  const int* cols = eidx + E;         // targets

  // workspace: [ybuf N*128 f][zbuf N*64 f][dinv N f][deg N i][off N+1 i][partial 512 i][goff G+1 i][csrsrc E i]
  float* ybuf   = (float*)d_ws;
  float* zbuf   = ybuf + (size_t)N * 128;
  float* dinv   = zbuf + (size_t)N * 64;
  int*   deg    = (int*)(dinv + N);
  int*   off    = deg + N;
  int*   partial= off + N + 1;
  int*   goff   = partial + 512;
  int*   csrsrc = goff + G + 1;

  const int B = 256;
  const int nb = (N + B - 1) / B;     // 391 <= 512

  hipMemsetAsync(deg, 0, (size_t)N * sizeof(int), stream);
  hipMemsetAsync(d_out, 0, (size_t)out_size * sizeof(float), stream);

  // CSR build + dinv + graph offsets
  k_count<<<(E + B - 1) / B, B, 0, stream>>>(cols, deg, E);
  k_blocksum<<<nb, B, 0, stream>>>(deg, partial, N);
  k_scanpartial<<<1, 512, 0, stream>>>(partial, nb);
  k_scanblock<<<nb, B, 0, stream>>>(deg, partial, off, dinv, N);
  k_fillcsr<<<(E + B - 1) / B, B, 0, stream>>>(rows, cols, deg, csrsrc, E);
  k_goff<<<(G + 1 + B - 1) / B, B, 0, stream>>>(batch, goff, N, G);

  // layer 1 transform
  k_gemm1<<<(N + 31) / 32, B, 0, stream>>>(x, W1, dinv, ybuf, N);
  // layer 1 aggregate + relu fused into layer 2 transform
  k_gemm2_fused<<<(N + 31) / 32, B, 0, stream>>>(ybuf, off, csrsrc, W2, dinv, b1, zbuf, N);
  // layer 2 aggregate + pool (atomic-light) + finalize
  k_aggpool<<<G * 8, B, 0, stream>>>(zbuf, off, csrsrc, dinv, goff, out, N);
  k_final<<<(out_size + B - 1) / B, B, 0, stream>>>(out, goff, b2, out_size);
}